// Round 1
// baseline (455.982 us; speedup 1.0000x reference)
//
#include <hip/hip_runtime.h>

// FCOS mask post-processor, MI355X. All decision-critical math in f64 to match np-f64 ref.

#define DEVI __device__ __forceinline__

constexpr int N_ = 2, C_ = 80, H_ = 32, W_ = 40, HW_ = H_ * W_, HWC_ = HW_ * C_;
constexpr int KTOP = 1000, M2_ = 196;
constexpr int IMH = 256, IMW = 320;          // image_h, image_w (fixed by setup_inputs)
constexpr int NBIN = 65536;
constexpr int BUFCAP = 4096;

// output layout (floats): bx[2][100][4] | sc[2][100] | lb[2][100] | prob[2][100][196] | vf[2][100]
constexpr int O_SC = 800, O_LB = 1000, O_PB = 1200, O_VF = 40400;

DEVI unsigned long long mapd(double v) {
  unsigned long long u = (unsigned long long)__double_as_longlong(v);
  return (u & 0x8000000000000000ull) ? ~u : (u | 0x8000000000000000ull);
}
DEVI double unmapd(unsigned long long k) {
  unsigned long long u = (k & 0x8000000000000000ull) ? (k ^ 0x8000000000000000ull) : ~k;
  return __longlong_as_double((long long)u);
}

// wave-aggregated histogram add (avoids same-address atomic serialization; wave=64)
DEVI void agg_add(unsigned* hist, int bin, bool want) {
  int lane = (int)(threadIdx.x & 63);
  while (true) {
    unsigned long long mask = __ballot(want);
    if (!mask) break;
    int leader = __builtin_ctzll(mask);
    int lb = __shfl(bin, leader);
    unsigned long long same = __ballot(want && (bin == lb));
    if (want && (lane == leader)) atomicAdd(hist + lb, (unsigned)__popcll(same));
    if (want && (bin == lb)) want = false;
  }
}

__global__ void k_init(unsigned* hist, unsigned* keepg, unsigned* selinfo) {
  int t = blockIdx.x * blockDim.x + threadIdx.x;
  if (t < N_ * NBIN) hist[t] = 0;
  if (t < N_ * 1024) keepg[t] = 0;
  if (t < 16) selinfo[t] = 0;
}

// exact cumulative bilinear row/col weight tables (weights are exact multiples of 1/16 in f32)
__global__ void k_tab(float* wr, float* wc) {
  int t = threadIdx.x;
  if (t < H_) {
    int r = t; float acc = 0.f; wr[0 * H_ + r] = 0.f;
    for (int x = 0; x < IMH; ++x) {
      float src = ((float)x + 0.5f) * ((float)H_ / (float)IMH) - 0.5f;
      src = fminf(fmaxf(src, 0.f), (float)(H_ - 1));
      int i0 = (int)floorf(src); int i1 = min(i0 + 1, H_ - 1);
      float lam = src - (float)i0;
      float w = ((r == i0) ? (1.f - lam) : 0.f) + ((r == i1) ? lam : 0.f);
      acc += w; wr[(x + 1) * H_ + r] = acc;
    }
  } else if (t < H_ + W_) {
    int q = t - H_; float acc = 0.f; wc[0 * W_ + q] = 0.f;
    for (int y = 0; y < IMW; ++y) {
      float src = ((float)y + 0.5f) * ((float)W_ / (float)IMW) - 0.5f;
      src = fminf(fmaxf(src, 0.f), (float)(W_ - 1));
      int i0 = (int)floorf(src); int i1 = min(i0 + 1, W_ - 1);
      float lam = src - (float)i0;
      float w = ((q == i0) ? (1.f - lam) : 0.f) + ((q == i1) ? lam : 0.f);
      acc += w; wc[(y + 1) * W_ + q] = acc;
    }
  }
}

// transpose [n][c][rq] -> [n][rq][c] with sigmoid
__global__ void k_mask(const float* bm, float* msig) {
  __shared__ float tile[32][33];
  int n = blockIdx.z;
  int rq0 = blockIdx.x * 32, c0 = blockIdx.y * 32;
  int tx = threadIdx.x, ty = threadIdx.y; // 32x8
  for (int i = 0; i < 4; ++i) {
    int cc = c0 + ty + i * 8, rq = rq0 + tx;
    if (cc < M2_ && rq < HW_) {
      float v = bm[((size_t)n * M2_ + cc) * HW_ + rq];
      tile[ty + i * 8][tx] = 1.f / (1.f + expf(-v));
    }
  }
  __syncthreads();
  for (int i = 0; i < 4; ++i) {
    int rq = rq0 + ty + i * 8, cc = c0 + tx;
    if (cc < M2_ && rq < HW_) msig[((size_t)n * HW_ + rq) * M2_ + cc] = tile[tx][ty + i * 8];
  }
}

// scores -> monotone-mapped f64 keys in [n][hw*C+c] layout
__global__ void k_keys(const float* cls, const float* cent, unsigned long long* keys) {
  int t = blockIdx.x * blockDim.x + threadIdx.x;
  if (t >= N_ * HWC_) return;
  int hw = t % HW_;
  int c = (t / HW_) % C_;
  int n = t / (C_ * HW_);
  double a = (double)cls[t];                       // input layout [n][c][hw] == t
  double s = 1.0 / (1.0 + exp(-a));
  double ce = 1.0 / (1.0 + exp(-(double)cent[n * HW_ + hw]));
  double v = (s > 0.05) ? s * ce : -1e9;
  keys[(size_t)n * HWC_ + (size_t)hw * C_ + c] = mapd(v);
}

__global__ void k_hist(const unsigned long long* keys, unsigned* hist) {
  int t = blockIdx.x * blockDim.x + threadIdx.x;
  int n = t / HWC_;
  unsigned long long k = keys[t];
  bool isCand = (k & 0x8000000000000000ull) != 0ull; // positive score (NEG entries skipped)
  agg_add(hist, (int)(k >> 48) + n * NBIN, isCand);
}

// per-image: find boundary bin D s.t. count(bin>D) < 1000 <= count(bin>=D)
__global__ __launch_bounds__(1024) void k_scan(const unsigned* hist, unsigned* selinfo) {
  int n = blockIdx.x;
  const unsigned* h = hist + (size_t)n * NBIN;
  int tid = threadIdx.x, lane = tid & 63, wid = tid >> 6;
  unsigned base = (unsigned)tid * 64;
  unsigned tot = 0;
  for (int j = 0; j < 64; ++j) tot += h[base + j];
  unsigned suf = tot; // wave-inclusive suffix (toward higher lanes = higher bins)
  for (int off = 1; off < 64; off <<= 1) {
    unsigned v = __shfl_down(suf, off);
    if (lane + off < 64) suf += v;
  }
  __shared__ unsigned wtot[16], wabove[16];
  if (lane == 0) wtot[wid] = suf;
  __syncthreads();
  if (tid == 0) {
    unsigned acc = 0;
    for (int wdx = 15; wdx >= 0; --wdx) { wabove[wdx] = acc; acc += wtot[wdx]; }
  }
  __syncthreads();
  unsigned running = (suf - tot) + wabove[wid]; // strictly above my top bin
  for (int j = 63; j >= 0; --j) {
    unsigned hb = h[base + j];
    if (running < 1000u && running + hb >= 1000u) {
      selinfo[n * 8 + 0] = base + (unsigned)j; // D
      selinfo[n * 8 + 1] = running;            // G
      selinfo[n * 8 + 2] = hb;                 // cnt
    }
    running += hb;
  }
  if (tid == 0) selinfo[n * 8 + 3] = 0; // compact counter
}

__global__ void k_compact(const unsigned long long* keys, unsigned* selinfo,
                          unsigned long long* bufk, unsigned* bufi) {
  int t = blockIdx.x * blockDim.x + threadIdx.x;
  int n = t / HWC_;
  int i = t % HWC_;
  unsigned long long k = keys[t];
  unsigned D = selinfo[n * 8 + 0];
  if ((unsigned)(k >> 48) >= D) {
    unsigned pos = atomicAdd(&selinfo[n * 8 + 3], 1u);
    if (pos < BUFCAP) { bufk[(size_t)n * BUFCAP + pos] = k; bufi[(size_t)n * BUFCAP + pos] = (unsigned)i; }
  }
}

// bitonic sort 4096 by (key desc, idx asc); emit exact stable top-1000
__global__ __launch_bounds__(1024) void k_sortemit(const unsigned long long* bufk, const unsigned* bufi,
                                                   const unsigned* selinfo,
                                                   unsigned long long* sk, unsigned* si) {
  __shared__ unsigned long long K[BUFCAP];
  __shared__ unsigned I[BUFCAP];
  int n = blockIdx.x, tid = threadIdx.x;
  unsigned cnt = selinfo[n * 8 + 3];
  if (cnt > BUFCAP) cnt = BUFCAP;
  for (int j = tid; j < BUFCAP; j += 1024) {
    if (j < (int)cnt) { K[j] = bufk[(size_t)n * BUFCAP + j]; I[j] = bufi[(size_t)n * BUFCAP + j]; }
    else { K[j] = 0ull; I[j] = 0xFFFFFFFFu; }
  }
  __syncthreads();
  for (int sz = 2; sz <= BUFCAP; sz <<= 1) {
    for (int st = sz >> 1; st > 0; st >>= 1) {
      for (int i = tid; i < BUFCAP; i += 1024) {
        int p = i ^ st;
        if (p > i) {
          bool up = ((i & sz) == 0);
          unsigned long long k1 = K[i], k2 = K[p];
          unsigned i1 = I[i], i2 = I[p];
          bool bef = (k1 > k2) || (k1 == k2 && i1 < i2);
          bool doswap = up ? (!bef) : bef;
          if (doswap) { K[i] = k2; K[p] = k1; I[i] = i2; I[p] = i1; }
        }
      }
      __syncthreads();
    }
  }
  for (int j = tid; j < 1024; j += 1024) { sk[n * 1024 + j] = K[j]; si[n * 1024 + j] = I[j]; }
}

__global__ __launch_bounds__(1024) void k_decode(const unsigned long long* sk, const unsigned* si,
                                                 const float* loc, const float* breg,
                                                 double* bxd, double* scd, int* lab, int* vld, int* rg) {
  int n = blockIdx.x, kk = threadIdx.x;
  if (kk >= KTOP) return;
  unsigned long long key = sk[n * 1024 + kk];
  unsigned idx = si[n * 1024 + kk];
  double v = unmapd(key);
  int valid = (v > -5e8) && (idx < (unsigned)HWC_);
  if (idx >= (unsigned)HWC_) idx = 0;
  int hw = (int)(idx / C_), c = (int)(idx % C_);
  double lx = (double)loc[hw * 2 + 0], ly = (double)loc[hw * 2 + 1];
  const float* rg4 = breg + (size_t)n * 4 * HW_;
  double r0 = (double)rg4[0 * HW_ + hw], r1 = (double)rg4[1 * HW_ + hw];
  double r2 = (double)rg4[2 * HW_ + hw], r3 = (double)rg4[3 * HW_ + hw];
  double b0 = lx - r0, b1 = ly - r1, b2 = lx + r2, b3 = ly + r3; // exact in f64
  double sc = valid ? sqrt(v) : 0.0;
  int bi0 = (int)b0, bi1 = (int)b1, bi2 = (int)b2, bi3 = (int)b3; // trunc toward 0 (astype int32)
  int x1 = max(bi0, 0), x2 = min(bi2, IMH - 1), y1 = max(bi1, 0), y2 = min(bi3, IMW - 1);
  int rok = (x1 < x2) && (y1 < x2) && (y1 < y2); // bug replicated
  int x1c = min(max(x1, 0), IMH), x2c = min(max(x2, 0), IMH);
  int y1c = min(max(y1, 0), IMW), y2c = min(max(y2, 0), IMW);
  int area = max((x2c - x1c) * (y2c - y1c), 1);
  double c0 = fmin(fmax(b0, 0.0), (double)(IMW - 1));
  double c1 = fmin(fmax(b1, 0.0), (double)(IMH - 1));
  double c2 = fmin(fmax(b2, 0.0), (double)(IMW - 1));
  double c3 = fmin(fmax(b3, 0.0), (double)(IMH - 1));
  size_t base = (size_t)n * 1024 + kk;
  bxd[base * 4 + 0] = c0; bxd[base * 4 + 1] = c1; bxd[base * 4 + 2] = c2; bxd[base * 4 + 3] = c3;
  scd[base] = sc; lab[base] = c + 1; vld[base] = valid;
  int* r8 = rg + base * 8;
  r8[0] = x1c; r8[1] = x2c; r8[2] = y1c; r8[3] = y2c; r8[4] = area; r8[5] = rok;
}

// per-(image,class) greedy NMS — classes are exactly independent (offset trick => cross-class IoU == 0)
__global__ void k_nms(const double* bxd, const int* lab, const int* vld, unsigned* keepg) {
  int cls = blockIdx.x + 1, n = blockIdx.y, tid = threadIdx.x; // 64 threads = 1 wave
  __shared__ int mk[KTOP];
  __shared__ double mb0[KTOP], mb1[KTOP], mb2[KTOP], mb3[KTOP], ma[KTOP];
  __shared__ unsigned char kept[KTOP];
  int m = 0;
  for (int base = 0; base < KTOP; base += 64) {
    int t = base + tid;
    bool pred = (t < KTOP) && (lab[n * 1024 + t] == cls) && (vld[n * 1024 + t] != 0);
    unsigned long long bb = __ballot(pred);
    if (pred) {
      int pos = m + (int)__popcll(bb & ((1ull << tid) - 1ull));
      mk[pos] = t;
      const double* p = bxd + ((size_t)n * 1024 + t) * 4;
      double b0 = p[0], b1 = p[1], b2 = p[2], b3 = p[3];
      mb0[pos] = b0; mb1[pos] = b1; mb2[pos] = b2; mb3[pos] = b3;
      ma[pos] = (b2 - b0 + 1.0) * (b3 - b1 + 1.0);
      kept[pos] = 1;
    }
    m += (int)__popcll(bb);
  }
  __syncthreads();
  for (int i = 0; i < m; ++i) {
    if (kept[i]) {
      double x1 = mb0[i], y1 = mb1[i], x2 = mb2[i], y2 = mb3[i], ai = ma[i];
      for (int j = i + 1 + tid; j < m; j += 64) {
        double ltx = fmax(x1, mb0[j]), lty = fmax(y1, mb1[j]);
        double rbx = fmin(x2, mb2[j]), rby = fmin(y2, mb3[j]);
        double iw = fmax(rbx - ltx + 1.0, 0.0), ih = fmax(rby - lty + 1.0, 0.0);
        double inter = iw * ih;
        double uni = ai + ma[j] - inter;
        if (inter / fmax(uni, 1e-6) > 0.6) kept[j] = 0;
      }
    }
    __syncthreads();
  }
  for (int i = tid; i < m; i += 64) keepg[n * 1024 + mk[i]] = (unsigned)kept[i];
}

// stable partition by keep flag -> sel[100]; emit boxes/scores/labels/vfin
__global__ __launch_bounds__(1024) void k_sel(const unsigned* keepg, const double* bxd,
                                              const double* scd, const int* lab,
                                              int* selA, int* vfA, float* out) {
  int n = blockIdx.x, tid = threadIdx.x, lane = tid & 63, wid = tid >> 6;
  int kp = (tid < KTOP) ? (int)keepg[n * 1024 + tid] : 0;
  unsigned long long b = __ballot(kp != 0);
  int posw = (int)__popcll(b & ((1ull << lane) - 1ull));
  __shared__ unsigned wcnt[16], woff[16], Stot;
  if (lane == 0) wcnt[wid] = (unsigned)__popcll(b);
  __syncthreads();
  if (tid == 0) { unsigned acc = 0; for (int i = 0; i < 16; ++i) { woff[i] = acc; acc += wcnt[i]; } Stot = acc; }
  __syncthreads();
  int posK = (int)woff[wid] + posw;
  int S = (int)Stot;
  __shared__ int lsel[100]; __shared__ int lvf[100];
  if (tid < KTOP) {
    if (kp) { if (posK < 100) { lsel[posK] = tid; lvf[posK] = 1; } }
    else { int slot = S + (tid - posK); if (slot < 100) { lsel[slot] = tid; lvf[slot] = 0; } }
  }
  __syncthreads();
  if (tid < 100) {
    int k = lsel[tid], vf = lvf[tid];
    selA[n * 128 + tid] = k; vfA[n * 128 + tid] = vf;
    const double* bb = bxd + ((size_t)n * 1024 + k) * 4;
    out[(n * 100 + tid) * 4 + 0] = (float)bb[0];
    out[(n * 100 + tid) * 4 + 1] = (float)bb[1];
    out[(n * 100 + tid) * 4 + 2] = (float)bb[2];
    out[(n * 100 + tid) * 4 + 3] = (float)bb[3];
    out[O_SC + n * 100 + tid] = vf ? (float)scd[n * 1024 + k] : 0.f;
    out[O_LB + n * 100 + tid] = (float)lab[n * 1024 + k];
    out[O_VF + n * 100 + tid] = (float)vf;
  }
}

// prob for the 200 selected boxes: separable region sum s = sum_r A(r) sum_q B(q) Msig[r][q][c]
__global__ void k_prob(const int* selA, const int* vfA, const int* rg, const float* msig,
                       const float* wr, const float* wc, float* out) {
  int t = blockIdx.x, n = blockIdx.y, tid = threadIdx.x;
  int k = selA[n * 128 + t], vf = vfA[n * 128 + t];
  const int* r8 = rg + ((size_t)n * 1024 + k) * 8;
  int x1c = r8[0], x2c = r8[1], y1c = r8[2], y2c = r8[3], area = r8[4], rok = r8[5];
  float* o = out + O_PB + (size_t)(n * 100 + t) * M2_;
  __shared__ float A[H_], B[W_];
  if (tid < H_) A[tid] = wr[x2c * H_ + tid] - wr[x1c * H_ + tid];
  else if (tid < H_ + W_) { int q = tid - H_; B[q] = wc[y2c * W_ + q] - wc[y1c * W_ + q]; }
  __syncthreads();
  if (tid < M2_) {
    float acc = 0.f;
    if (rok && vf) {
      for (int r = 0; r < H_; ++r) {
        float ar = A[r];
        if (ar == 0.f) continue;
        const float* mrow = msig + ((size_t)(n * H_ + r) * W_) * M2_ + tid;
        float rs = 0.f;
        for (int q = 0; q < W_; ++q) {
          float bq = B[q];
          if (bq != 0.f) rs += bq * mrow[q * M2_];
        }
        acc += ar * rs;
      }
      acc /= (float)area;
    }
    o[tid] = acc;
  }
}

extern "C" void kernel_launch(void* const* d_in, const int* in_sizes, int n_in,
                              void* d_out, int out_size, void* d_ws, size_t ws_size,
                              hipStream_t stream) {
  (void)in_sizes; (void)n_in; (void)out_size; (void)ws_size;
  const float* locations = (const float*)d_in[0];
  const float* box_cls   = (const float*)d_in[1];
  const float* box_reg   = (const float*)d_in[2];
  const float* cent      = (const float*)d_in[3];
  const float* box_mask  = (const float*)d_in[4];
  float* out = (float*)d_out;

  char* ws = (char*)d_ws;
  size_t off = 0;
  auto alloc = [&](size_t bytes) -> void* {
    void* p = ws + off;
    off = (off + bytes + 255) & ~(size_t)255;
    return p;
  };
  unsigned long long* keys = (unsigned long long*)alloc((size_t)N_ * HWC_ * 8);
  unsigned* hist           = (unsigned*)alloc((size_t)N_ * NBIN * 4);
  unsigned* keepg          = (unsigned*)alloc((size_t)N_ * 1024 * 4);
  unsigned* selinfo        = (unsigned*)alloc(16 * 4);
  unsigned long long* bufk = (unsigned long long*)alloc((size_t)N_ * BUFCAP * 8);
  unsigned* bufi           = (unsigned*)alloc((size_t)N_ * BUFCAP * 4);
  unsigned long long* sk   = (unsigned long long*)alloc((size_t)N_ * 1024 * 8);
  unsigned* si             = (unsigned*)alloc((size_t)N_ * 1024 * 4);
  double* bxd              = (double*)alloc((size_t)N_ * 1024 * 4 * 8);
  double* scd              = (double*)alloc((size_t)N_ * 1024 * 8);
  int* lab                 = (int*)alloc((size_t)N_ * 1024 * 4);
  int* vld                 = (int*)alloc((size_t)N_ * 1024 * 4);
  int* rg                  = (int*)alloc((size_t)N_ * 1024 * 8 * 4);
  int* selA                = (int*)alloc((size_t)N_ * 128 * 4);
  int* vfA                 = (int*)alloc((size_t)N_ * 128 * 4);
  float* msig              = (float*)alloc((size_t)N_ * HW_ * M2_ * 4);
  float* wr                = (float*)alloc((size_t)(IMH + 1) * H_ * 4);
  float* wc                = (float*)alloc((size_t)(IMW + 1) * W_ * 4);

  k_init<<<256, 512, 0, stream>>>(hist, keepg, selinfo);
  k_tab<<<1, 128, 0, stream>>>(wr, wc);
  k_mask<<<dim3(HW_ / 32, (M2_ + 31) / 32, N_), dim3(32, 8), 0, stream>>>(box_mask, msig);
  k_keys<<<(N_ * HWC_) / 256, 256, 0, stream>>>(box_cls, cent, keys);
  k_hist<<<(N_ * HWC_) / 256, 256, 0, stream>>>(keys, hist);
  k_scan<<<N_, 1024, 0, stream>>>(hist, selinfo);
  k_compact<<<(N_ * HWC_) / 256, 256, 0, stream>>>(keys, selinfo, bufk, bufi);
  k_sortemit<<<N_, 1024, 0, stream>>>(bufk, bufi, selinfo, sk, si);
  k_decode<<<N_, 1024, 0, stream>>>(sk, si, locations, box_reg, bxd, scd, lab, vld, rg);
  k_nms<<<dim3(C_, N_), 64, 0, stream>>>(bxd, lab, vld, keepg);
  k_sel<<<N_, 1024, 0, stream>>>(keepg, bxd, scd, lab, selA, vfA, out);
  k_prob<<<dim3(100, N_), 256, 0, stream>>>(selA, vfA, rg, msig, wr, wc, out);
}

// Round 2
// 169.409 us; speedup vs baseline: 2.6916x; 2.6916x over previous
//
#include <hip/hip_runtime.h>

#define DEVI __device__ __forceinline__

constexpr int N_ = 2, C_ = 80, H_ = 32, W_ = 40, HW_ = H_ * W_, HWC_ = HW_ * C_;
constexpr int KTOP = 1000, M2_ = 196;
constexpr int IMH = 256, IMW = 320;
constexpr int BUFCAP = 4096;
constexpr int NB = 2048; // float-derived bins

// output layout (floats): bx[2][100][4] | sc[2][100] | lb[2][100] | prob[2][100][196] | vf[2][100]
constexpr int O_SC = 800, O_LB = 1000, O_PB = 1200, O_VF = 40400;

DEVI unsigned long long mapd(double v) {
  unsigned long long u = (unsigned long long)__double_as_longlong(v);
  return (u & 0x8000000000000000ull) ? ~u : (u | 0x8000000000000000ull);
}
DEVI double unmapd(unsigned long long k) {
  unsigned long long u = (k & 0x8000000000000000ull) ? (k ^ 0x8000000000000000ull) : ~k;
  return __longlong_as_double((long long)u);
}
// bin from top 16 bits of the f32 cast of the (positive) score: well-spread, monotone
DEVI int binof(unsigned long long k) {
  double v = unmapd(k);
  unsigned b = __float_as_uint((float)v);
  int bin = (int)(b >> 16) - 0x3800;
  return bin < 0 ? 0 : (bin > NB - 1 ? NB - 1 : bin);
}

// ---- fused: keys (f64 sigmoid scores) + mask transpose+sigmoid + bilinear weight tables ----
__global__ __launch_bounds__(256) void k_pre(const float* cls, const float* cent, const float* bm,
                                             unsigned long long* keys, float* msig,
                                             float* wr, float* wc) {
  __shared__ float tile[32][33];
  int b = blockIdx.x, tid = threadIdx.x;
  if (b < 800) {
    int t = b * 256 + tid;                 // [n][c][hw] linear
    int hw = t % HW_;
    int n = t / HWC_;
    double a = (double)cls[t];
    double s = 1.0 / (1.0 + exp(-a));
    double ce = 1.0 / (1.0 + exp(-(double)cent[n * HW_ + hw]));
    double v = (s > 0.05) ? s * ce : -1e9;
    keys[t] = mapd(v);                     // stored in input layout (coalesced)
  } else if (b < 1360) {
    int bb = b - 800;
    int n = bb / 280; bb %= 280;
    int rqt = bb / 7, ct = bb % 7;
    int tx = tid & 31, ty = tid >> 5;      // 32x8
    int rq0 = rqt * 32, c0 = ct * 32;
    for (int i = 0; i < 4; ++i) {
      int cc = c0 + ty + i * 8, rq = rq0 + tx;
      if (cc < M2_ && rq < HW_) {
        float v = bm[((size_t)n * M2_ + cc) * HW_ + rq];
        tile[ty + i * 8][tx] = 1.f / (1.f + expf(-v));
      }
    }
    __syncthreads();
    for (int i = 0; i < 4; ++i) {
      int rq = rq0 + ty + i * 8, cc = c0 + tx;
      if (cc < M2_ && rq < HW_) msig[((size_t)n * HW_ + rq) * M2_ + cc] = tile[tx][ty + i * 8];
    }
  } else {
    int t = tid;
    if (t < H_) {
      int r = t; float acc = 0.f; wr[0 * H_ + r] = 0.f;
      for (int x = 0; x < IMH; ++x) {
        float src = ((float)x + 0.5f) * ((float)H_ / (float)IMH) - 0.5f;
        src = fminf(fmaxf(src, 0.f), (float)(H_ - 1));
        int i0 = (int)floorf(src); int i1 = min(i0 + 1, H_ - 1);
        float lam = src - (float)i0;
        float w = ((r == i0) ? (1.f - lam) : 0.f) + ((r == i1) ? lam : 0.f);
        acc += w; wr[(x + 1) * H_ + r] = acc;
      }
    } else if (t < H_ + W_) {
      int q = t - H_; float acc = 0.f; wc[0 * W_ + q] = 0.f;
      for (int y = 0; y < IMW; ++y) {
        float src = ((float)y + 0.5f) * ((float)W_ / (float)IMW) - 0.5f;
        src = fminf(fmaxf(src, 0.f), (float)(W_ - 1));
        int i0 = (int)floorf(src); int i1 = min(i0 + 1, W_ - 1);
        float lam = src - (float)i0;
        float w = ((q == i0) ? (1.f - lam) : 0.f) + ((q == i1) ? lam : 0.f);
        acc += w; wc[(y + 1) * W_ + q] = acc;
      }
    }
  }
}

// ---- per-image: LDS hist -> suffix scan -> compact -> bitonic sort -> decode top-1000 ----
__global__ __launch_bounds__(1024) void k_select(const unsigned long long* keys,
                                                 const float* loc, const float* breg,
                                                 double* bxd, double* scd, int* lab, int* vld,
                                                 int* rg, unsigned* keepg) {
  __shared__ unsigned hist[NB];
  __shared__ unsigned long long K[BUFCAP];
  __shared__ unsigned I[BUFCAP];
  __shared__ unsigned wtot[16], wabove[16];
  __shared__ unsigned sD, sCnt;
  int n = blockIdx.x, tid = threadIdx.x, lane = tid & 63, wid = tid >> 6;
  const unsigned long long* kb = keys + (size_t)n * HWC_;

  keepg[n * 1024 + tid] = 0;
  for (int j = tid; j < NB; j += 1024) hist[j] = 0;
  if (tid == 0) { sD = 0; sCnt = 0; }
  __syncthreads();

  // pass 1: histogram candidates
  for (int j = tid; j < HWC_; j += 1024) {
    unsigned long long k = kb[j];
    if (k >> 63) atomicAdd(&hist[binof(k)], 1u);
  }
  __syncthreads();

  // suffix scan over 2048 bins (thread owns bins 2tid, 2tid+1; higher tid = higher bin)
  unsigned a = hist[2 * tid], bv = hist[2 * tid + 1], s = a + bv;
  unsigned suf = s;
  for (int off = 1; off < 64; off <<= 1) {
    unsigned v = __shfl_down(suf, off);
    if (lane + off < 64) suf += v;
  }
  if (lane == 0) wtot[wid] = suf;
  __syncthreads();
  if (tid == 0) { unsigned acc = 0; for (int w = 15; w >= 0; --w) { wabove[w] = acc; acc += wtot[w]; } }
  __syncthreads();
  unsigned above = (suf - s) + wabove[wid];          // count in bins > 2tid+1
  if (above < 1000u && above + bv >= 1000u) sD = (unsigned)(2 * tid + 1);
  if (above + bv < 1000u && above + bv + a >= 1000u) sD = (unsigned)(2 * tid);
  __syncthreads();
  unsigned D = sD;                                   // total<1000 -> D=0 (take all candidates)

  // pass 2: compact bin>=D (order fixed by sort)
  for (int j = tid; j < HWC_; j += 1024) {
    unsigned long long k = kb[j];
    if ((k >> 63) && (unsigned)binof(k) >= D) {
      unsigned pos = atomicAdd(&sCnt, 1u);
      if (pos < BUFCAP) {
        K[pos] = k;
        int c = j / HW_, hw = j % HW_;
        I[pos] = (unsigned)(hw * C_ + c);            // logical [HW,C] flat index (top_k order)
      }
    }
  }
  __syncthreads();
  int cnt = (int)sCnt; if (cnt > BUFCAP) cnt = BUFCAP;
  int P = 1024; while (P < cnt) P <<= 1;
  for (int j = tid; j < P; j += 1024)
    if (j >= cnt) { K[j] = 0ull; I[j] = 0xFFFFFFFFu; }
  __syncthreads();

  // bitonic sort P entries by (key desc, idx asc)
  for (int sz = 2; sz <= P; sz <<= 1) {
    for (int st = sz >> 1; st > 0; st >>= 1) {
      for (int i = tid; i < P; i += 1024) {
        int p = i ^ st;
        if (p > i) {
          bool up = ((i & sz) == 0);
          unsigned long long k1 = K[i], k2 = K[p];
          unsigned i1 = I[i], i2 = I[p];
          bool bef = (k1 > k2) || (k1 == k2 && i1 < i2);
          bool doswap = up ? (!bef) : bef;
          if (doswap) { K[i] = k2; K[p] = k1; I[i] = i2; I[p] = i1; }
        }
      }
      __syncthreads();
    }
  }

  // decode top-1000 (f64, exact vs np ref)
  if (tid < KTOP) {
    unsigned long long key = K[tid];
    unsigned idx = I[tid];
    double v = unmapd(key);
    int valid = (v > -5e8) && (idx < (unsigned)HWC_);
    if (idx >= (unsigned)HWC_) idx = 0;
    int hw = (int)(idx / C_), c = (int)(idx % C_);
    double lx = (double)loc[hw * 2 + 0], ly = (double)loc[hw * 2 + 1];
    const float* rg4 = breg + (size_t)n * 4 * HW_;
    double r0 = (double)rg4[0 * HW_ + hw], r1 = (double)rg4[1 * HW_ + hw];
    double r2 = (double)rg4[2 * HW_ + hw], r3 = (double)rg4[3 * HW_ + hw];
    double b0 = lx - r0, b1 = ly - r1, b2 = lx + r2, b3 = ly + r3;
    double sc = valid ? sqrt(v) : 0.0;
    int bi0 = (int)b0, bi1 = (int)b1, bi2 = (int)b2, bi3 = (int)b3;
    int x1 = max(bi0, 0), x2 = min(bi2, IMH - 1), y1 = max(bi1, 0), y2 = min(bi3, IMW - 1);
    int rok = (x1 < x2) && (y1 < x2) && (y1 < y2);   // ref bug replicated
    int x1c = min(max(x1, 0), IMH), x2c = min(max(x2, 0), IMH);
    int y1c = min(max(y1, 0), IMW), y2c = min(max(y2, 0), IMW);
    int area = max((x2c - x1c) * (y2c - y1c), 1);
    double c0 = fmin(fmax(b0, 0.0), (double)(IMW - 1));
    double c1 = fmin(fmax(b1, 0.0), (double)(IMH - 1));
    double c2 = fmin(fmax(b2, 0.0), (double)(IMW - 1));
    double c3 = fmin(fmax(b3, 0.0), (double)(IMH - 1));
    size_t base = (size_t)n * 1024 + tid;
    bxd[base * 4 + 0] = c0; bxd[base * 4 + 1] = c1; bxd[base * 4 + 2] = c2; bxd[base * 4 + 3] = c3;
    scd[base] = sc; lab[base] = c + 1; vld[base] = valid;
    int* r8 = rg + base * 8;
    r8[0] = x1c; r8[1] = x2c; r8[2] = y1c; r8[3] = y2c; r8[4] = area; r8[5] = rok;
  }
}

// ---- per-(image,class) greedy NMS (classes exactly independent via offset trick) ----
__global__ void k_nms(const double* bxd, const int* lab, const int* vld, unsigned* keepg) {
  int cls = blockIdx.x + 1, n = blockIdx.y, tid = threadIdx.x; // 64 threads = 1 wave
  __shared__ int mk[KTOP];
  __shared__ double mb0[KTOP], mb1[KTOP], mb2[KTOP], mb3[KTOP], ma[KTOP];
  __shared__ unsigned char kept[KTOP];
  int m = 0;
  for (int base = 0; base < KTOP; base += 64) {
    int t = base + tid;
    bool pred = (t < KTOP) && (lab[n * 1024 + t] == cls) && (vld[n * 1024 + t] != 0);
    unsigned long long bb = __ballot(pred);
    if (pred) {
      int pos = m + (int)__popcll(bb & ((1ull << tid) - 1ull));
      mk[pos] = t;
      const double* p = bxd + ((size_t)n * 1024 + t) * 4;
      double b0 = p[0], b1 = p[1], b2 = p[2], b3 = p[3];
      mb0[pos] = b0; mb1[pos] = b1; mb2[pos] = b2; mb3[pos] = b3;
      ma[pos] = (b2 - b0 + 1.0) * (b3 - b1 + 1.0);
      kept[pos] = 1;
    }
    m += (int)__popcll(bb);
  }
  __syncthreads();
  for (int i = 0; i < m; ++i) {
    if (kept[i]) {
      double x1 = mb0[i], y1 = mb1[i], x2 = mb2[i], y2 = mb3[i], ai = ma[i];
      for (int j = i + 1 + tid; j < m; j += 64) {
        double ltx = fmax(x1, mb0[j]), lty = fmax(y1, mb1[j]);
        double rbx = fmin(x2, mb2[j]), rby = fmin(y2, mb3[j]);
        double iw = fmax(rbx - ltx + 1.0, 0.0), ih = fmax(rby - lty + 1.0, 0.0);
        double inter = iw * ih;
        double uni = ai + ma[j] - inter;
        if (inter / fmax(uni, 1e-6) > 0.6) kept[j] = 0;
      }
    }
    __syncthreads();
  }
  for (int i = tid; i < m; i += 64) keepg[n * 1024 + mk[i]] = (unsigned)kept[i];
}

// ---- fused: stable partition (redundant per block, parallel) + per-slot outputs + mask prob ----
__global__ __launch_bounds__(256) void k_finish(const unsigned* keepg, const double* bxd,
                                                const double* scd, const int* lab, const int* rg,
                                                const float* msig, const float* wr, const float* wc,
                                                float* out) {
  int t = blockIdx.x, n = blockIdx.y, tid = threadIdx.x, lane = tid & 63, wid = tid >> 6;
  __shared__ int lsel[100], lvf[100];
  __shared__ unsigned woff[4]; __shared__ unsigned sS;
  __shared__ float A[H_], B[W_];

  // each thread owns contiguous entries [4tid, 4tid+4)
  int i0 = tid * 4;
  unsigned ff[4]; int lc = 0;
  for (int j = 0; j < 4; ++j) {
    int i = i0 + j;
    ff[j] = (i < KTOP) ? keepg[n * 1024 + i] : 0u;
    lc += (int)ff[j];
  }
  unsigned pre = (unsigned)lc;
  for (int off = 1; off < 64; off <<= 1) {
    unsigned v = __shfl_up(pre, off);
    if (lane >= off) pre += v;
  }
  if (lane == 63) woff[wid] = pre;
  __syncthreads();
  if (tid == 0) { unsigned acc = 0; for (int w = 0; w < 4; ++w) { unsigned tmp = woff[w]; woff[w] = acc; acc += tmp; } sS = acc; }
  __syncthreads();
  int kpre = (int)(woff[wid] + pre - (unsigned)lc);  // keeps before entry i0
  int S = (int)sS;
  for (int j = 0; j < 4; ++j) {
    int i = i0 + j;
    if (i < KTOP) {
      if (ff[j]) { if (kpre < 100) { lsel[kpre] = i; lvf[kpre] = 1; } kpre++; }
      else { int slot = S + (i - kpre); if (slot < 100) { lsel[slot] = i; lvf[slot] = 0; } }
    }
  }
  __syncthreads();

  int k = lsel[t], vf = lvf[t];
  if (tid == 0) {
    const double* bb = bxd + ((size_t)n * 1024 + k) * 4;
    out[(n * 100 + t) * 4 + 0] = (float)bb[0];
    out[(n * 100 + t) * 4 + 1] = (float)bb[1];
    out[(n * 100 + t) * 4 + 2] = (float)bb[2];
    out[(n * 100 + t) * 4 + 3] = (float)bb[3];
    out[O_SC + n * 100 + t] = vf ? (float)scd[n * 1024 + k] : 0.f;
    out[O_LB + n * 100 + t] = (float)lab[n * 1024 + k];
    out[O_VF + n * 100 + t] = (float)vf;
  }
  const int* r8 = rg + ((size_t)n * 1024 + k) * 8;
  int x1c = r8[0], x2c = r8[1], y1c = r8[2], y2c = r8[3], area = r8[4], rok = r8[5];
  if (tid < H_) A[tid] = wr[x2c * H_ + tid] - wr[x1c * H_ + tid];
  else if (tid < H_ + W_) { int q = tid - H_; B[q] = wc[y2c * W_ + q] - wc[y1c * W_ + q]; }
  __syncthreads();
  if (tid < M2_) {
    float acc = 0.f;
    if (rok && vf) {
      for (int r = 0; r < H_; ++r) {
        float ar = A[r];
        if (ar == 0.f) continue;
        const float* mrow = msig + ((size_t)(n * H_ + r) * W_) * M2_ + tid;
        float rs = 0.f;
        for (int q = 0; q < W_; ++q) {
          float bq = B[q];
          if (bq != 0.f) rs += bq * mrow[q * M2_];
        }
        acc += ar * rs;
      }
      acc /= (float)area;
    }
    out[O_PB + (size_t)(n * 100 + t) * M2_ + tid] = acc;
  }
}

extern "C" void kernel_launch(void* const* d_in, const int* in_sizes, int n_in,
                              void* d_out, int out_size, void* d_ws, size_t ws_size,
                              hipStream_t stream) {
  (void)in_sizes; (void)n_in; (void)out_size; (void)ws_size;
  const float* locations = (const float*)d_in[0];
  const float* box_cls   = (const float*)d_in[1];
  const float* box_reg   = (const float*)d_in[2];
  const float* cent      = (const float*)d_in[3];
  const float* box_mask  = (const float*)d_in[4];
  float* out = (float*)d_out;

  char* ws = (char*)d_ws;
  size_t off = 0;
  auto alloc = [&](size_t bytes) -> void* {
    void* p = ws + off;
    off = (off + bytes + 255) & ~(size_t)255;
    return p;
  };
  unsigned long long* keys = (unsigned long long*)alloc((size_t)N_ * HWC_ * 8);
  unsigned* keepg          = (unsigned*)alloc((size_t)N_ * 1024 * 4);
  double* bxd              = (double*)alloc((size_t)N_ * 1024 * 4 * 8);
  double* scd              = (double*)alloc((size_t)N_ * 1024 * 8);
  int* lab                 = (int*)alloc((size_t)N_ * 1024 * 4);
  int* vld                 = (int*)alloc((size_t)N_ * 1024 * 4);
  int* rg                  = (int*)alloc((size_t)N_ * 1024 * 8 * 4);
  float* msig              = (float*)alloc((size_t)N_ * HW_ * M2_ * 4);
  float* wr                = (float*)alloc((size_t)(IMH + 1) * H_ * 4);
  float* wc                = (float*)alloc((size_t)(IMW + 1) * W_ * 4);

  k_pre<<<1361, 256, 0, stream>>>(box_cls, cent, box_mask, keys, msig, wr, wc);
  k_select<<<N_, 1024, 0, stream>>>(keys, locations, box_reg, bxd, scd, lab, vld, rg, keepg);
  k_nms<<<dim3(C_, N_), 64, 0, stream>>>(bxd, lab, vld, keepg);
  k_finish<<<dim3(100, N_), 256, 0, stream>>>(keepg, bxd, scd, lab, rg, msig, wr, wc, out);
}